// Round 6
// baseline (177.302 us; speedup 1.0000x reference)
//
#include <hip/hip_runtime.h>
#include <hip/hip_bf16.h>
#include <math.h>

#define C_   128
#define HW_  4096
#define OC_  100
#define NSTAT_ 32768.0f

typedef __bf16 bf16x8 __attribute__((ext_vector_type(8)));
typedef __bf16 bf16x4 __attribute__((ext_vector_type(4)));
typedef float  f32x4  __attribute__((ext_vector_type(4)));

// ---------------- K1: 1x1 conv via MFMA bf16 -> t1c[b][px][64] bf16 + stats + wprep --------
// grid 512 = b(8) x chunk(64 of 64px); 256 thr = 4 waves, wave = one 16-px m-tile, N=64.
__global__ __launch_bounds__(256, 4) void k_conv1(const float* __restrict__ x,
                                                  const float* __restrict__ w,
                                                  const float* __restrict__ wenc,
                                                  __bf16* __restrict__ t1c,
                                                  float* __restrict__ csum,
                                                  float* __restrict__ csq,
                                                  __bf16* __restrict__ wprep) {
    __shared__ __bf16 xt[64 * 128];   // [px][ic], 256B rows, 16B-block XOR swizzle
    __shared__ __bf16 wt[64 * 128];   // [oc][ic], same swizzle
    __shared__ float sS[64], sQ[64];

    int blk = blockIdx.x;
    int b = blk & 7;
    int chunk = blk >> 3;             // 0..63
    int px0 = chunk * 64;
    int tid = threadIdx.x;
    if (tid < 64) { sS[tid] = 0.f; sQ[tid] = 0.f; }

    // pack enc weights -> wprep[oc 112][k 576], k = tap*64+ic  (blocks 0..62, 1024 each)
    if (blk < 63) {
#pragma unroll
        for (int u = 0; u < 4; ++u) {
            int idx = blk * 1024 + u * 256 + tid;   // < 64512 = 112*576
            int oc = idx / 576, k = idx - oc * 576;
            int tap = k >> 6, ic = k & 63;
            wprep[idx] = (oc < OC_) ? (__bf16)wenc[((size_t)oc * 64 + ic) * 9 + tap]
                                    : (__bf16)0.f;
        }
    }

    // stage comp_w (64 oc x 128 ic fp32) -> wt bf16: 2048 float4 jobs
#pragma unroll
    for (int it = 0; it < 8; ++it) {
        int j = it * 256 + tid;       // 0..2047
        int oc = j >> 5, f = j & 31;
        float4 v = *(const float4*)(w + (size_t)oc * 128 + f * 4);
        int blki = (f >> 1) ^ (oc & 15);
        bf16x4 st;
        st[0] = (__bf16)v.x; st[1] = (__bf16)v.y; st[2] = (__bf16)v.z; st[3] = (__bf16)v.w;
        *(bf16x4*)&wt[oc * 128 + blki * 8 + (f & 1) * 4] = st;
    }
    // stage x tile (64 px x 128 ic) -> xt bf16 (transpose 4x4 in regs), 512 jobs x 16 floats
#pragma unroll
    for (int it = 0; it < 2; ++it) {
        int j = it * 256 + tid;
        int px4 = (j & 15) * 4, icq = j >> 4;   // icq 0..31
        const float* xp = x + ((size_t)b * C_ + icq * 4) * HW_ + px0 + px4;
        float4 v0 = *(const float4*)(xp);
        float4 v1 = *(const float4*)(xp + HW_);
        float4 v2 = *(const float4*)(xp + 2 * HW_);
        float4 v3 = *(const float4*)(xp + 3 * HW_);
        float r0[4] = {v0.x, v0.y, v0.z, v0.w};
        float r1[4] = {v1.x, v1.y, v1.z, v1.w};
        float r2_[4] = {v2.x, v2.y, v2.z, v2.w};
        float r3[4] = {v3.x, v3.y, v3.z, v3.w};
#pragma unroll
        for (int r2 = 0; r2 < 4; ++r2) {
            int px = px4 + r2;
            int blki = (icq >> 1) ^ (px & 15);
            bf16x4 st;
            st[0] = (__bf16)r0[r2]; st[1] = (__bf16)r1[r2];
            st[2] = (__bf16)r2_[r2]; st[3] = (__bf16)r3[r2];
            *(bf16x4*)&xt[px * 128 + blki * 8 + (icq & 1) * 4] = st;
        }
    }
    __syncthreads();

    int lane = tid & 63, wv = tid >> 6;
    int p = lane & 15, q = lane >> 4;

    f32x4 acc[4];
#pragma unroll
    for (int n = 0; n < 4; ++n) acc[n] = (f32x4){0.f, 0.f, 0.f, 0.f};

#pragma unroll
    for (int kk = 0; kk < 4; ++kk) {
        int blki = (kk * 4 + q) ^ p;
        bf16x8 a = *(const bf16x8*)&xt[(wv * 16 + p) * 128 + blki * 8];
#pragma unroll
        for (int n = 0; n < 4; ++n) {
            bf16x8 bb = *(const bf16x8*)&wt[(n * 16 + p) * 128 + blki * 8];
            acc[n] = __builtin_amdgcn_mfma_f32_16x16x32_bf16(a, bb, acc[n], 0, 0, 0);
        }
    }

    // D: col(oc within tile) = p, row(px within tile) = q*4+rg
    __bf16* t1b = t1c + ((size_t)b * HW_ + px0 + wv * 16) * 64;
#pragma unroll
    for (int n = 0; n < 4; ++n) {
        float s = 0.f, qq = 0.f;
#pragma unroll
        for (int rg = 0; rg < 4; ++rg) {
            float v = acc[n][rg];
            t1b[(size_t)(q * 4 + rg) * 64 + n * 16 + p] = (__bf16)v;
            s += v; qq += v * v;
        }
        s += __shfl_down(s, 32, 64);  s += __shfl_down(s, 16, 64);
        qq += __shfl_down(qq, 32, 64); qq += __shfl_down(qq, 16, 64);
        if (lane < 16) {
            atomicAdd(&sS[n * 16 + p], s);
            atomicAdd(&sQ[n * 16 + p], qq);
        }
    }
    __syncthreads();
    if (tid < 64) {
        atomicAdd(&csum[tid], sS[tid]);
        atomicAdd(&csq[tid], sQ[tid]);
    }
}

// ---------------- K2: 3x3 conv MFMA; barrier-free K-loop, B direct from L2 ----------------
// grid 512 = b(8) x tile(64 of 8x8 px); 256 thr = 4 waves.
// wprep is 129 KB and L2-resident: B fragments load straight from global into MFMA operands
// (per instr: 16 full 64B lines, perfectly coalesced). No bt LDS buffer, no in-loop barriers.
// Epilogue: transpose through LDS -> t2c[b][k][pxl][4] written as contiguous 128B rows.
// R5 BUG FIX: epilogue tile needs 25*260*4 = 26,000 B; R5 aliased it onto the 14,400 B bf16
// xt -> 11.6 KB LDS overflow trampling lsc/esuml (absmax 5.0). Buffer now declared at fp32
// size; bf16 staging tile aliases the front of it. LDS total ~27.4 KB -> still 4 blocks/CU.
__global__ __launch_bounds__(256, 4) void k_conv3(const __bf16* __restrict__ t1c,
                                                  const __bf16* __restrict__ wprep,
                                                  const float* __restrict__ csum,
                                                  const float* __restrict__ csq,
                                                  const float* __restrict__ cg,
                                                  const float* __restrict__ cb,
                                                  float* __restrict__ t2c,
                                                  float* __restrict__ esum,
                                                  float* __restrict__ esq) {
    __shared__ float xtf[25 * 260];            // 26,000 B; front 14,400 B aliased as bf16 xt
    __bf16* xt = (__bf16*)xtf;
    __shared__ float lsc[64], lsh[64];
    __shared__ float esuml[112], esql[112];

    int blk = blockIdx.x;
    int b = blk & 7;
    int tile = blk >> 3;
    int ty0 = (tile >> 3) * 8, tx0 = (tile & 7) * 8;
    int tid = threadIdx.x;
    if (tid < 112) { esuml[tid] = 0.f; esql[tid] = 0.f; }
    if (tid >= 128 && tid < 192) {
        int c = tid - 128;
        float invN = 1.0f / NSTAT_;
        float m = csum[c] * invN;
        float v = csq[c] * invN - m * m;
        float rs = rsqrtf(v + 1e-5f);
        float sc = cg[c] * rs;
        lsc[c] = sc;
        lsh[c] = cb[c] - m * sc;
    }
    __syncthreads();   // lsc/lsh ready for staging

    // stage BN+SiLU(t1) 10x10 halo -> xt  (1600 jobs of 4 ic)
    const __bf16* tb = t1c + (size_t)b * HW_ * 64;
#pragma unroll
    for (int it = 0; it < 7; ++it) {
        int idx = it * 256 + tid;
        if (idx < 1600) {
            int pxi = idx >> 4, f4 = idx & 15;
            int yy = pxi / 10, xx = pxi - yy * 10;
            int gy = ty0 + yy - 1, gx = tx0 + xx - 1;
            float o0 = 0.f, o1 = 0.f, o2 = 0.f, o3 = 0.f;
            if (gy >= 0 && gy < 64 && gx >= 0 && gx < 64) {
                bf16x4 v = *(const bf16x4*)(tb + ((size_t)(gy << 6) + gx) * 64 + f4 * 4);
                float4 sc = *(const float4*)(lsc + f4 * 4);
                float4 sh = *(const float4*)(lsh + f4 * 4);
                float u;
                u = fmaf((float)v[0], sc.x, sh.x); o0 = u / (1.f + __expf(-u));
                u = fmaf((float)v[1], sc.y, sh.y); o1 = u / (1.f + __expf(-u));
                u = fmaf((float)v[2], sc.z, sh.z); o2 = u / (1.f + __expf(-u));
                u = fmaf((float)v[3], sc.w, sh.w); o3 = u / (1.f + __expf(-u));
            }
            bf16x4 st;
            st[0] = (__bf16)o0; st[1] = (__bf16)o1; st[2] = (__bf16)o2; st[3] = (__bf16)o3;
            *(bf16x4*)&xt[pxi * 72 + f4 * 4] = st;
        }
    }
    __syncthreads();   // xt ready

    int lane = tid & 63, wv = tid >> 6;
    int p = lane & 15, q = lane >> 4;
    int ya = 2 * wv + (p >> 3), xa = p & 7;
    const __bf16* wpl = wprep + p * 576 + q * 8;   // lane-constant B base

    f32x4 acc[7];
#pragma unroll
    for (int n = 0; n < 7; ++n) acc[n] = (f32x4){0.f, 0.f, 0.f, 0.f};

#pragma unroll
    for (int kk = 0; kk < 18; ++kk) {
        const int tap = kk >> 1, ich = (kk & 1) * 32;
        const int ky = tap / 3, kx = tap - ky * 3;
        bf16x8 a0 = *(const bf16x8*)&xt[((ya + ky) * 10 + xa + kx) * 72 + ich + q * 8];
#pragma unroll
        for (int n = 0; n < 7; ++n) {
            bf16x8 bb = *(const bf16x8*)(wpl + n * 9216 + kk * 32);  // L2-hit, coalesced
            acc[n] = __builtin_amdgcn_mfma_f32_16x16x32_bf16(a0, bb, acc[n], 0, 0, 0);
        }
    }
    __syncthreads();   // all xt reads done; reuse buffer as fp32 transpose tile

    // epilogue 1: acc -> LDS tile [k5 25][py 8][pxx 8][sch 4], stride 260 fl/k5 (bank-clean)
#pragma unroll
    for (int n = 0; n < 7; ++n) {
        int oc = n * 16 + p;
        int k5 = oc >> 2, sch = oc & 3;
        bool wr = oc < OC_;
        float s = 0.f, qq = 0.f;
#pragma unroll
        for (int rg = 0; rg < 4; ++rg) {
            int mp = q * 4 + rg;
            float v = acc[n][rg];
            if (wr) xtf[k5 * 260 + (2 * wv + (mp >> 3)) * 32 + (mp & 7) * 4 + sch] = v;
            s += v; qq += v * v;
        }
        s += __shfl_down(s, 32, 64);  s += __shfl_down(s, 16, 64);
        qq += __shfl_down(qq, 32, 64); qq += __shfl_down(qq, 16, 64);
        if (lane < 16) {
            atomicAdd(&esuml[n * 16 + lane], s);
            atomicAdd(&esql[n * 16 + lane], qq);
        }
    }
    __syncthreads();   // xtf + esuml ready

    // epilogue 2: coalesced t2c write: 1600 float4 jobs = 25 k-planes x 64 px
    float* t2b = t2c + (size_t)b * 25 * HW_ * 4;
#pragma unroll
    for (int it = 0; it < 7; ++it) {
        int idx = it * 256 + tid;
        if (idx < 1600) {
            int k5 = idx >> 6, pix = idx & 63;
            f32x4 v = *(const f32x4*)&xtf[k5 * 260 + pix * 4];
            int gy = ty0 + (pix >> 3), gx = tx0 + (pix & 7);
            *(f32x4*)&t2b[((size_t)k5 * HW_ + (gy << 6) + gx) * 4] = v;
        }
    }
    if (tid < 112) {
        atomicAdd(&esum[tid], esuml[tid]);
        atomicAdd(&esq[tid], esql[tid]);
    }
}

// ---------------- K3: BN2 + softmax + reassembly; subpixel-PAIR, 512-thread blocks --------
// 8-wave blocks + single 32KB LDS buffer: 2 co-resident blocks give 16 waves/CU (the
// VGPR=128 maximum) -> LDS pipe saturated. Stage-to-stage prefetch via regs (pf/pg).
// grid 512 = b(8) x tile(16: 4x4 of 16x16 lowres) x cq(4 of 32ch); thread = subpixel pair.
// t2c logits [b][k][pxl][4]: softmax loads fully coalesced float2.
__global__ __launch_bounds__(512, 2) void k_carafe(const float* __restrict__ x,
                                                   const float* __restrict__ t2c,
                                                   const float* __restrict__ esum,
                                                   const float* __restrict__ esq,
                                                   const float* __restrict__ eg,
                                                   const float* __restrict__ eb,
                                                   float* __restrict__ out) {
    __shared__ float xt[400 * 20];     // [halo px 20x20][16 ch pad 20] = 32000 B
    __shared__ float esc[112], esh[112];

    int blk = blockIdx.x;
    int b = blk & 7;
    int r = blk >> 3;                  // 0..63
    int tile = r & 15;
    int cq = r >> 4;                   // 0..3 channel quarter (32 ch = 2 stages of 16)
    int tx0 = (tile & 3) * 16, ty0 = (tile >> 2) * 16;
    int tid = threadIdx.x;
    if (tid < 112) {
        float invN = 1.0f / NSTAT_;
        float m = esum[tid] * invN;
        float v = esq[tid] * invN - m * m;
        float rs = rsqrtf(v + 1e-5f);
        float sc = (tid < OC_) ? eg[tid] * rs : 0.f;
        esc[tid] = sc;
        esh[tid] = (tid < OC_) ? eb[tid] - m * sc : 0.f;
    }

    int t0 = tid & 1, px = tid >> 1;      // t0 = si (output row within 2x2), px 0..255
    int pxx = px & 15, py = px >> 4;      // py 0..15
    int iy = ty0 + py, jx = tx0 + pxx;
    int pxl = (iy << 6) + jx;

    const float* xb = x + (size_t)b * C_ * HW_;

    // issue stage-0 x loads into regs now; they complete under the softmax below
    f32x4 pf[4];
#pragma unroll
    for (int it = 0; it < 4; ++it) {
        int idx = it * 512 + tid;          // 1600 jobs = 400 halo px x 4 c-quads
        if (idx < 1600) {
            int c4 = idx / 400;
            int hp = idx - c4 * 400;
            int yy = hp / 20, xx = hp - yy * 20;
            int gy = ty0 - 2 + yy, gx = tx0 - 2 + xx;
            f32x4 st = {0.f, 0.f, 0.f, 0.f};
            if (gy >= 0 && gy < 64 && gx >= 0 && gx < 64) {
                size_t base = (size_t)(cq * 32 + c4 * 4) * HW_ + (gy << 6) + gx;
                st[0] = xb[base];
                st[1] = xb[base + HW_];
                st[2] = xb[base + 2 * HW_];
                st[3] = xb[base + 3 * HW_];
            }
            pf[it] = st;
        }
    }
    __syncthreads();   // esc/esh ready

    // two softmaxes (channels 2*t0, 2*t0+1); coalesced: wave reads 512B per tap plane
    float wA[25], wB[25];
    {
        const float* t2p = t2c + (size_t)b * 25 * HW_ * 4 + (size_t)pxl * 4 + 2 * t0;
        int cA = 2 * t0, cB = 2 * t0 + 1;
        float mxA = -1e30f, mxB = -1e30f;
#pragma unroll
        for (int k = 0; k < 25; ++k) {
            float2 v = *(const float2*)(t2p + (size_t)k * HW_ * 4);
            float lA = fmaf(v.x, esc[4 * k + cA], esh[4 * k + cA]);
            float lB = fmaf(v.y, esc[4 * k + cB], esh[4 * k + cB]);
            wA[k] = lA; wB[k] = lB;
            mxA = fmaxf(mxA, lA); mxB = fmaxf(mxB, lB);
        }
        float sA = 0.f, sB = 0.f;
#pragma unroll
        for (int k = 0; k < 25; ++k) {
            float eA = __expf(wA[k] - mxA);
            float eB = __expf(wB[k] - mxB);
            wA[k] = eA; wB[k] = eB;
            sA += eA; sB += eB;
        }
        float iA = 1.f / sA, iB = 1.f / sB;
#pragma unroll
        for (int k = 0; k < 25; ++k) { wA[k] *= iA; wB[k] *= iB; }
    }

    // stage-0 data -> LDS
#pragma unroll
    for (int it = 0; it < 4; ++it) {
        int idx = it * 512 + tid;
        if (idx < 1600) {
            int c4 = idx / 400;
            int hp = idx - c4 * 400;
            *(f32x4*)&xt[hp * 20 + c4 * 4] = pf[it];
        }
    }
    __syncthreads();   // xt = stage 0

    int i0 = iy * 2 + t0;
    float* op = out + (size_t)b * C_ * 16384 + (size_t)i0 * 128 + jx * 2;
    int cbase = cq * 32;

    // prefetch stage-1 channels into regs (completes under stage-0 compute)
    f32x4 pg[4];
#pragma unroll
    for (int it = 0; it < 4; ++it) {
        int idx = it * 512 + tid;
        if (idx < 1600) {
            int c4 = idx / 400;
            int hp = idx - c4 * 400;
            int yy = hp / 20, xx = hp - yy * 20;
            int gy = ty0 - 2 + yy, gx = tx0 - 2 + xx;
            f32x4 st = {0.f, 0.f, 0.f, 0.f};
            if (gy >= 0 && gy < 64 && gx >= 0 && gx < 64) {
                size_t base = (size_t)(cbase + 16 + c4 * 4) * HW_ + (gy << 6) + gx;
                st[0] = xb[base];
                st[1] = xb[base + HW_];
                st[2] = xb[base + 2 * HW_];
                st[3] = xb[base + 3 * HW_];
            }
            pg[it] = st;
        }
    }

    // ---- stage 0 compute ----
    {
        float accA[16], accB[16];
#pragma unroll
        for (int e = 0; e < 16; ++e) { accA[e] = 0.f; accB[e] = 0.f; }
#pragma unroll
        for (int dy = 0; dy < 5; ++dy)
#pragma unroll
            for (int dx = 0; dx < 5; ++dx) {
                int pos = (py + dy) * 20 + pxx + dx;
                float a = wA[dy * 5 + dx], bw = wB[dy * 5 + dx];
#pragma unroll
                for (int c4 = 0; c4 < 4; ++c4) {
                    f32x4 xv = *(const f32x4*)&xt[pos * 20 + c4 * 4];
                    accA[c4 * 4 + 0] = fmaf(a, xv[0], accA[c4 * 4 + 0]);
                    accA[c4 * 4 + 1] = fmaf(a, xv[1], accA[c4 * 4 + 1]);
                    accA[c4 * 4 + 2] = fmaf(a, xv[2], accA[c4 * 4 + 2]);
                    accA[c4 * 4 + 3] = fmaf(a, xv[3], accA[c4 * 4 + 3]);
                    accB[c4 * 4 + 0] = fmaf(bw, xv[0], accB[c4 * 4 + 0]);
                    accB[c4 * 4 + 1] = fmaf(bw, xv[1], accB[c4 * 4 + 1]);
                    accB[c4 * 4 + 2] = fmaf(bw, xv[2], accB[c4 * 4 + 2]);
                    accB[c4 * 4 + 3] = fmaf(bw, xv[3], accB[c4 * 4 + 3]);
                }
            }
#pragma unroll
        for (int e = 0; e < 16; ++e) {
            float2 st2;
            st2.x = accA[e]; st2.y = accB[e];
            *(float2*)&op[(size_t)(cbase + e) * 16384] = st2;
        }
    }
    __syncthreads();   // all reads of stage 0 done

    // stage-1 data -> LDS
#pragma unroll
    for (int it = 0; it < 4; ++it) {
        int idx = it * 512 + tid;
        if (idx < 1600) {
            int c4 = idx / 400;
            int hp = idx - c4 * 400;
            *(f32x4*)&xt[hp * 20 + c4 * 4] = pg[it];
        }
    }
    __syncthreads();   // xt = stage 1

    // ---- stage 1 compute ----
    {
        float accA[16], accB[16];
#pragma unroll
        for (int e = 0; e < 16; ++e) { accA[e] = 0.f; accB[e] = 0.f; }
#pragma unroll
        for (int dy = 0; dy < 5; ++dy)
#pragma unroll
            for (int dx = 0; dx < 5; ++dx) {
                int pos = (py + dy) * 20 + pxx + dx;
                float a = wA[dy * 5 + dx], bw = wB[dy * 5 + dx];
#pragma unroll
                for (int c4 = 0; c4 < 4; ++c4) {
                    f32x4 xv = *(const f32x4*)&xt[pos * 20 + c4 * 4];
                    accA[c4 * 4 + 0] = fmaf(a, xv[0], accA[c4 * 4 + 0]);
                    accA[c4 * 4 + 1] = fmaf(a, xv[1], accA[c4 * 4 + 1]);
                    accA[c4 * 4 + 2] = fmaf(a, xv[2], accA[c4 * 4 + 2]);
                    accA[c4 * 4 + 3] = fmaf(a, xv[3], accA[c4 * 4 + 3]);
                    accB[c4 * 4 + 0] = fmaf(bw, xv[0], accB[c4 * 4 + 0]);
                    accB[c4 * 4 + 1] = fmaf(bw, xv[1], accB[c4 * 4 + 1]);
                    accB[c4 * 4 + 2] = fmaf(bw, xv[2], accB[c4 * 4 + 2]);
                    accB[c4 * 4 + 3] = fmaf(bw, xv[3], accB[c4 * 4 + 3]);
                }
            }
#pragma unroll
        for (int e = 0; e < 16; ++e) {
            float2 st2;
            st2.x = accA[e]; st2.y = accB[e];
            *(float2*)&op[(size_t)(cbase + 16 + e) * 16384] = st2;
        }
    }
}

extern "C" void kernel_launch(void* const* d_in, const int* in_sizes, int n_in,
                              void* d_out, int out_size, void* d_ws, size_t ws_size,
                              hipStream_t stream) {
    const float* x      = (const float*)d_in[0];
    const float* comp_w = (const float*)d_in[1];
    const float* comp_g = (const float*)d_in[2];
    const float* comp_b = (const float*)d_in[3];
    const float* enc_w  = (const float*)d_in[4];
    const float* enc_g  = (const float*)d_in[5];
    const float* enc_b  = (const float*)d_in[6];
    float* out = (float*)d_out;

    float* ws = (float*)d_ws;
    __bf16* t1c = (__bf16*)ws;             // 8*4096*64 bf16 = 4 MB
    float* t2c  = ws + 1048576;            // 8*25*4096*4 fp32 = 13.1 MB (transposed layout)
    float* st   = ws + 1048576 + 3670016;
    float* csum = st;                      // 64
    float* csq  = st + 64;                 // 64
    float* esum = st + 128;                // 112
    float* esq  = st + 240;                // 112
    __bf16* wprep = (__bf16*)(st + 352);   // 112*576 bf16

    hipMemsetAsync(st, 0, 352 * sizeof(float), stream);
    k_conv1<<<512, 256, 0, stream>>>(x, comp_w, enc_w, t1c, csum, csq, wprep);
    k_conv3<<<512, 256, 0, stream>>>(t1c, wprep, csum, csq, comp_g, comp_b, t2c, esum, esq);
    k_carafe<<<512, 512, 0, stream>>>(x, t2c, esum, esq, enc_g, enc_b, out);
}

// Round 7
// 158.608 us; speedup vs baseline: 1.1179x; 1.1179x over previous
//
#include <hip/hip_runtime.h>
#include <hip/hip_bf16.h>
#include <math.h>

#define C_   128
#define HW_  4096
#define OC_  100
#define NSTAT_ 32768.0f

typedef __bf16 bf16x8 __attribute__((ext_vector_type(8)));
typedef __bf16 bf16x4 __attribute__((ext_vector_type(4)));
typedef float  f32x4  __attribute__((ext_vector_type(4)));

// ---------------- K1: 1x1 conv via MFMA bf16 -> t1c[b][px][64] bf16 + stats + wprep --------
// grid 512 = b(8) x chunk(64 of 64px); 256 thr = 4 waves, wave = one 16-px m-tile, N=64.
__global__ __launch_bounds__(256, 4) void k_conv1(const float* __restrict__ x,
                                                  const float* __restrict__ w,
                                                  const float* __restrict__ wenc,
                                                  __bf16* __restrict__ t1c,
                                                  float* __restrict__ csum,
                                                  float* __restrict__ csq,
                                                  __bf16* __restrict__ wprep) {
    __shared__ __bf16 xt[64 * 128];   // [px][ic], 256B rows, 16B-block XOR swizzle
    __shared__ __bf16 wt[64 * 128];   // [oc][ic], same swizzle
    __shared__ float sS[64], sQ[64];

    int blk = blockIdx.x;
    int b = blk & 7;
    int chunk = blk >> 3;             // 0..63
    int px0 = chunk * 64;
    int tid = threadIdx.x;
    if (tid < 64) { sS[tid] = 0.f; sQ[tid] = 0.f; }

    // pack enc weights -> wprep[oc 112][k 576], k = tap*64+ic  (blocks 0..62, 1024 each)
    if (blk < 63) {
#pragma unroll
        for (int u = 0; u < 4; ++u) {
            int idx = blk * 1024 + u * 256 + tid;   // < 64512 = 112*576
            int oc = idx / 576, k = idx - oc * 576;
            int tap = k >> 6, ic = k & 63;
            wprep[idx] = (oc < OC_) ? (__bf16)wenc[((size_t)oc * 64 + ic) * 9 + tap]
                                    : (__bf16)0.f;
        }
    }

    // stage comp_w (64 oc x 128 ic fp32) -> wt bf16: 2048 float4 jobs
#pragma unroll
    for (int it = 0; it < 8; ++it) {
        int j = it * 256 + tid;       // 0..2047
        int oc = j >> 5, f = j & 31;
        float4 v = *(const float4*)(w + (size_t)oc * 128 + f * 4);
        int blki = (f >> 1) ^ (oc & 15);
        bf16x4 st;
        st[0] = (__bf16)v.x; st[1] = (__bf16)v.y; st[2] = (__bf16)v.z; st[3] = (__bf16)v.w;
        *(bf16x4*)&wt[oc * 128 + blki * 8 + (f & 1) * 4] = st;
    }
    // stage x tile (64 px x 128 ic) -> xt bf16 (transpose 4x4 in regs), 512 jobs x 16 floats
#pragma unroll
    for (int it = 0; it < 2; ++it) {
        int j = it * 256 + tid;
        int px4 = (j & 15) * 4, icq = j >> 4;   // icq 0..31
        const float* xp = x + ((size_t)b * C_ + icq * 4) * HW_ + px0 + px4;
        float4 v0 = *(const float4*)(xp);
        float4 v1 = *(const float4*)(xp + HW_);
        float4 v2 = *(const float4*)(xp + 2 * HW_);
        float4 v3 = *(const float4*)(xp + 3 * HW_);
        float r0[4] = {v0.x, v0.y, v0.z, v0.w};
        float r1[4] = {v1.x, v1.y, v1.z, v1.w};
        float r2_[4] = {v2.x, v2.y, v2.z, v2.w};
        float r3[4] = {v3.x, v3.y, v3.z, v3.w};
#pragma unroll
        for (int r2 = 0; r2 < 4; ++r2) {
            int px = px4 + r2;
            int blki = (icq >> 1) ^ (px & 15);
            bf16x4 st;
            st[0] = (__bf16)r0[r2]; st[1] = (__bf16)r1[r2];
            st[2] = (__bf16)r2_[r2]; st[3] = (__bf16)r3[r2];
            *(bf16x4*)&xt[px * 128 + blki * 8 + (icq & 1) * 4] = st;
        }
    }
    __syncthreads();

    int lane = tid & 63, wv = tid >> 6;
    int p = lane & 15, q = lane >> 4;

    f32x4 acc[4];
#pragma unroll
    for (int n = 0; n < 4; ++n) acc[n] = (f32x4){0.f, 0.f, 0.f, 0.f};

#pragma unroll
    for (int kk = 0; kk < 4; ++kk) {
        int blki = (kk * 4 + q) ^ p;
        bf16x8 a = *(const bf16x8*)&xt[(wv * 16 + p) * 128 + blki * 8];
#pragma unroll
        for (int n = 0; n < 4; ++n) {
            bf16x8 bb = *(const bf16x8*)&wt[(n * 16 + p) * 128 + blki * 8];
            acc[n] = __builtin_amdgcn_mfma_f32_16x16x32_bf16(a, bb, acc[n], 0, 0, 0);
        }
    }

    // D: col(oc within tile) = p, row(px within tile) = q*4+rg
    __bf16* t1b = t1c + ((size_t)b * HW_ + px0 + wv * 16) * 64;
#pragma unroll
    for (int n = 0; n < 4; ++n) {
        float s = 0.f, qq = 0.f;
#pragma unroll
        for (int rg = 0; rg < 4; ++rg) {
            float v = acc[n][rg];
            t1b[(size_t)(q * 4 + rg) * 64 + n * 16 + p] = (__bf16)v;
            s += v; qq += v * v;
        }
        s += __shfl_down(s, 32, 64);  s += __shfl_down(s, 16, 64);
        qq += __shfl_down(qq, 32, 64); qq += __shfl_down(qq, 16, 64);
        if (lane < 16) {
            atomicAdd(&sS[n * 16 + p], s);
            atomicAdd(&sQ[n * 16 + p], qq);
        }
    }
    __syncthreads();
    if (tid < 64) {
        atomicAdd(&csum[tid], sS[tid]);
        atomicAdd(&csq[tid], sQ[tid]);
    }
}

// ---------------- K2: 3x3 conv MFMA; LDS-dbuf B staging, oc-HALF split for occupancy ------
// R6 lesson: B-direct-from-global serialized (VGPR 52, MfmaUtil 3%, 48us). Restore the
// proven reg-prefetch -> ds_write double-buffer, and fix the grid starvation (512 blocks =
// 2/CU): split oc into halves -> grid 1024 = b(8) x tile(64) x half(2) = 4 blocks/CU.
// bt row stride 40 bf16 (not 32): stride-32 made every bb ds_read an 8-way bank conflict
// (16p dwords mod 32 collapses to {0,16}); stride 40 -> 20p mod 32 distinct per 8-lane phase.
// Epilogue: LDS transpose -> t2c[b][k][pxl][4] contiguous 128B rows (R6 scheme, kept).
__global__ __launch_bounds__(256, 4) void k_conv3(const __bf16* __restrict__ t1c,
                                                  const __bf16* __restrict__ wprep,
                                                  const float* __restrict__ csum,
                                                  const float* __restrict__ csq,
                                                  const float* __restrict__ cg,
                                                  const float* __restrict__ cb,
                                                  float* __restrict__ t2c,
                                                  float* __restrict__ esum,
                                                  float* __restrict__ esq) {
    // union buffer: phase A = xt bf16 14400 B + bt 2x(64x40) bf16 10240 B = 24640 B
    //               phase B = xtf fp32 [<=16][260] = 16640 B  (aliases front)
    __shared__ float shbuf[6160];
    __bf16* xt  = (__bf16*)shbuf;
    __bf16* btb = (__bf16*)((char*)shbuf + 14400);   // btb[buf*2560 + idx]
    float*  xtf = shbuf;
    __shared__ float lsc[64], lsh[64];
    __shared__ float esuml[112], esql[112];

    int blk = blockIdx.x;
    int b = blk & 7;
    int rest = blk >> 3;
    int tile = rest & 63;
    int half = rest >> 6;                       // 0: oc 0..63, 1: oc 64..111
    int ty0 = (tile >> 3) * 8, tx0 = (tile & 7) * 8;
    int tid = threadIdx.x;
    const int oc0 = half * 64;
    const int NOC = half ? 48 : 64;
    const int NT  = half ? 3 : 4;               // n-tiles of 16 oc

    if (tid < 112) { esuml[tid] = 0.f; esql[tid] = 0.f; }
    if (tid >= 128 && tid < 192) {
        int c = tid - 128;
        float invN = 1.0f / NSTAT_;
        float m = csum[c] * invN;
        float v = csq[c] * invN - m * m;
        float rs = rsqrtf(v + 1e-5f);
        float sc = cg[c] * rs;
        lsc[c] = sc;
        lsh[c] = cb[c] - m * sc;
    }

    // staging role: one 16B chunk per thread per k-chunk
    int soc = tid >> 2, spart = tid & 3;
    bool sact = soc < NOC;
    int sdst = soc * 40 + spart * 8;
    const __bf16* wsrc = wprep + (size_t)(oc0 + soc) * 576 + spart * 8;

    // prologue: stage B chunk 0 into buf 0 (no lsc dependency)
    if (sact) *(bf16x8*)&btb[sdst] = *(const bf16x8*)(wsrc);
    __syncthreads();   // lsc/lsh ready

    // stage BN+SiLU(t1) 10x10 halo -> xt  (1600 jobs of 4 ic)
    const __bf16* tb = t1c + (size_t)b * HW_ * 64;
#pragma unroll
    for (int it = 0; it < 7; ++it) {
        int idx = it * 256 + tid;
        if (idx < 1600) {
            int pxi = idx >> 4, f4 = idx & 15;
            int yy = pxi / 10, xx = pxi - yy * 10;
            int gy = ty0 + yy - 1, gx = tx0 + xx - 1;
            float o0 = 0.f, o1 = 0.f, o2 = 0.f, o3 = 0.f;
            if (gy >= 0 && gy < 64 && gx >= 0 && gx < 64) {
                bf16x4 v = *(const bf16x4*)(tb + ((size_t)(gy << 6) + gx) * 64 + f4 * 4);
                float4 sc = *(const float4*)(lsc + f4 * 4);
                float4 sh = *(const float4*)(lsh + f4 * 4);
                float u;
                u = fmaf((float)v[0], sc.x, sh.x); o0 = u / (1.f + __expf(-u));
                u = fmaf((float)v[1], sc.y, sh.y); o1 = u / (1.f + __expf(-u));
                u = fmaf((float)v[2], sc.z, sh.z); o2 = u / (1.f + __expf(-u));
                u = fmaf((float)v[3], sc.w, sh.w); o3 = u / (1.f + __expf(-u));
            }
            bf16x4 st;
            st[0] = (__bf16)o0; st[1] = (__bf16)o1; st[2] = (__bf16)o2; st[3] = (__bf16)o3;
            *(bf16x4*)&xt[pxi * 72 + f4 * 4] = st;
        }
    }
    __syncthreads();   // xt + bt[0] ready

    int lane = tid & 63, wv = tid >> 6;
    int p = lane & 15, q = lane >> 4;
    int ya = 2 * wv + (p >> 3), xa = p & 7;

    f32x4 acc[4];
#pragma unroll
    for (int n = 0; n < 4; ++n) acc[n] = (f32x4){0.f, 0.f, 0.f, 0.f};

#pragma unroll
    for (int kk = 0; kk < 18; ++kk) {
        const int cur = kk & 1;
        // prefetch B chunk kk+1 into regs (coalesced 16B L2 loads, latency under MFMA)
        bf16x8 r0;
        if (kk < 17 && sact) r0 = *(const bf16x8*)(wsrc + (kk + 1) * 32);
        // compute from bt[cur]
        const int tap = kk >> 1, ich = (kk & 1) * 32;
        const int ky = tap / 3, kx = tap - ky * 3;
        bf16x8 a0 = *(const bf16x8*)&xt[((ya + ky) * 10 + xa + kx) * 72 + ich + q * 8];
        const __bf16* btc = btb + cur * 2560;
#pragma unroll
        for (int n = 0; n < 4; ++n) {
            if (n < NT) {
                bf16x8 bb = *(const bf16x8*)&btc[(n * 16 + p) * 40 + q * 8];
                acc[n] = __builtin_amdgcn_mfma_f32_16x16x32_bf16(a0, bb, acc[n], 0, 0, 0);
            }
        }
        if (kk < 17) {
            if (sact) *(bf16x8*)&btb[(1 - cur) * 2560 + sdst] = r0;
            __syncthreads();
        }
    }
    __syncthreads();   // all xt/bt reads done; reuse buffer as fp32 transpose tile

    // epilogue 1: acc -> LDS tile [k5l][py 8][pxx 8][sch 4], stride 260 fl (bank-clean)
#pragma unroll
    for (int n = 0; n < 4; ++n) {
        if (n < NT) {
            int ocl = n * 16 + p;              // oc - oc0
            int oc = oc0 + ocl;
            int k5l = ocl >> 2, sch = ocl & 3;
            bool wr = oc < OC_;
            float s = 0.f, qq = 0.f;
#pragma unroll
            for (int rg = 0; rg < 4; ++rg) {
                int mp = q * 4 + rg;
                float v = acc[n][rg];
                if (wr) xtf[k5l * 260 + (2 * wv + (mp >> 3)) * 32 + (mp & 7) * 4 + sch] = v;
                s += v; qq += v * v;
            }
            s += __shfl_down(s, 32, 64);  s += __shfl_down(s, 16, 64);
            qq += __shfl_down(qq, 32, 64); qq += __shfl_down(qq, 16, 64);
            if (lane < 16) {
                atomicAdd(&esuml[oc0 + n * 16 + lane], s);
                atomicAdd(&esql[oc0 + n * 16 + lane], qq);
            }
        }
    }
    __syncthreads();   // xtf + esuml ready

    // epilogue 2: coalesced t2c write: NK5 x 64 float4 jobs (k5 global = oc0/4 + k5l)
    const int NK5 = half ? 9 : 16;             // half1: oc 64..99 -> k5 16..24
    const int jobs = NK5 * 64;
    float* t2b = t2c + (size_t)b * 25 * HW_ * 4;
#pragma unroll
    for (int it = 0; it < 4; ++it) {
        int idx = it * 256 + tid;
        if (idx < jobs) {
            int k5l = idx >> 6, pix = idx & 63;
            f32x4 v = *(const f32x4*)&xtf[k5l * 260 + pix * 4];
            int gy = ty0 + (pix >> 3), gx = tx0 + (pix & 7);
            *(f32x4*)&t2b[((size_t)(half * 16 + k5l) * HW_ + (gy << 6) + gx) * 4] = v;
        }
    }
    if (tid >= oc0 && tid < oc0 + NOC) {
        atomicAdd(&esum[tid], esuml[tid]);
        atomicAdd(&esq[tid], esql[tid]);
    }
}

// ---------------- K3: BN2 + softmax + reassembly; subpixel-PAIR, 512-thread blocks --------
// 8-wave blocks + single 32KB LDS buffer: 2 co-resident blocks give 16 waves/CU (the
// VGPR=128 maximum) -> LDS pipe saturated. Stage-to-stage prefetch via regs (pf/pg).
// grid 512 = b(8) x tile(16: 4x4 of 16x16 lowres) x cq(4 of 32ch); thread = subpixel pair.
// t2c logits [b][k][pxl][4]: softmax loads fully coalesced float2.
__global__ __launch_bounds__(512, 2) void k_carafe(const float* __restrict__ x,
                                                   const float* __restrict__ t2c,
                                                   const float* __restrict__ esum,
                                                   const float* __restrict__ esq,
                                                   const float* __restrict__ eg,
                                                   const float* __restrict__ eb,
                                                   float* __restrict__ out) {
    __shared__ float xt[400 * 20];     // [halo px 20x20][16 ch pad 20] = 32000 B
    __shared__ float esc[112], esh[112];

    int blk = blockIdx.x;
    int b = blk & 7;
    int r = blk >> 3;                  // 0..63
    int tile = r & 15;
    int cq = r >> 4;                   // 0..3 channel quarter (32 ch = 2 stages of 16)
    int tx0 = (tile & 3) * 16, ty0 = (tile >> 2) * 16;
    int tid = threadIdx.x;
    if (tid < 112) {
        float invN = 1.0f / NSTAT_;
        float m = esum[tid] * invN;
        float v = esq[tid] * invN - m * m;
        float rs = rsqrtf(v + 1e-5f);
        float sc = (tid < OC_) ? eg[tid] * rs : 0.f;
        esc[tid] = sc;
        esh[tid] = (tid < OC_) ? eb[tid] - m * sc : 0.f;
    }

    int t0 = tid & 1, px = tid >> 1;      // t0 = si (output row within 2x2), px 0..255
    int pxx = px & 15, py = px >> 4;      // py 0..15
    int iy = ty0 + py, jx = tx0 + pxx;
    int pxl = (iy << 6) + jx;

    const float* xb = x + (size_t)b * C_ * HW_;

    // issue stage-0 x loads into regs now; they complete under the softmax below
    f32x4 pf[4];
#pragma unroll
    for (int it = 0; it < 4; ++it) {
        int idx = it * 512 + tid;          // 1600 jobs = 400 halo px x 4 c-quads
        if (idx < 1600) {
            int c4 = idx / 400;
            int hp = idx - c4 * 400;
            int yy = hp / 20, xx = hp - yy * 20;
            int gy = ty0 - 2 + yy, gx = tx0 - 2 + xx;
            f32x4 st = {0.f, 0.f, 0.f, 0.f};
            if (gy >= 0 && gy < 64 && gx >= 0 && gx < 64) {
                size_t base = (size_t)(cq * 32 + c4 * 4) * HW_ + (gy << 6) + gx;
                st[0] = xb[base];
                st[1] = xb[base + HW_];
                st[2] = xb[base + 2 * HW_];
                st[3] = xb[base + 3 * HW_];
            }
            pf[it] = st;
        }
    }
    __syncthreads();   // esc/esh ready

    // two softmaxes (channels 2*t0, 2*t0+1); coalesced: wave reads 512B per tap plane
    float wA[25], wB[25];
    {
        const float* t2p = t2c + (size_t)b * 25 * HW_ * 4 + (size_t)pxl * 4 + 2 * t0;
        int cA = 2 * t0, cB = 2 * t0 + 1;
        float mxA = -1e30f, mxB = -1e30f;
#pragma unroll
        for (int k = 0; k < 25; ++k) {
            float2 v = *(const float2*)(t2p + (size_t)k * HW_ * 4);
            float lA = fmaf(v.x, esc[4 * k + cA], esh[4 * k + cA]);
            float lB = fmaf(v.y, esc[4 * k + cB], esh[4 * k + cB]);
            wA[k] = lA; wB[k] = lB;
            mxA = fmaxf(mxA, lA); mxB = fmaxf(mxB, lB);
        }
        float sA = 0.f, sB = 0.f;
#pragma unroll
        for (int k = 0; k < 25; ++k) {
            float eA = __expf(wA[k] - mxA);
            float eB = __expf(wB[k] - mxB);
            wA[k] = eA; wB[k] = eB;
            sA += eA; sB += eB;
        }
        float iA = 1.f / sA, iB = 1.f / sB;
#pragma unroll
        for (int k = 0; k < 25; ++k) { wA[k] *= iA; wB[k] *= iB; }
    }

    // stage-0 data -> LDS
#pragma unroll
    for (int it = 0; it < 4; ++it) {
        int idx = it * 512 + tid;
        if (idx < 1600) {
            int c4 = idx / 400;
            int hp = idx - c4 * 400;
            *(f32x4*)&xt[hp * 20 + c4 * 4] = pf[it];
        }
    }
    __syncthreads();   // xt = stage 0

    int i0 = iy * 2 + t0;
    float* op = out + (size_t)b * C_ * 16384 + (size_t)i0 * 128 + jx * 2;
    int cbase = cq * 32;

    // prefetch stage-1 channels into regs (completes under stage-0 compute)
    f32x4 pg[4];
#pragma unroll
    for (int it = 0; it < 4; ++it) {
        int idx = it * 512 + tid;
        if (idx < 1600) {
            int c4 = idx / 400;
            int hp = idx - c4 * 400;
            int yy = hp / 20, xx = hp - yy * 20;
            int gy = ty0 - 2 + yy, gx = tx0 - 2 + xx;
            f32x4 st = {0.f, 0.f, 0.f, 0.f};
            if (gy >= 0 && gy < 64 && gx >= 0 && gx < 64) {
                size_t base = (size_t)(cbase + 16 + c4 * 4) * HW_ + (gy << 6) + gx;
                st[0] = xb[base];
                st[1] = xb[base + HW_];
                st[2] = xb[base + 2 * HW_];
                st[3] = xb[base + 3 * HW_];
            }
            pg[it] = st;
        }
    }

    // ---- stage 0 compute ----
    {
        float accA[16], accB[16];
#pragma unroll
        for (int e = 0; e < 16; ++e) { accA[e] = 0.f; accB[e] = 0.f; }
#pragma unroll
        for (int dy = 0; dy < 5; ++dy)
#pragma unroll
            for (int dx = 0; dx < 5; ++dx) {
                int pos = (py + dy) * 20 + pxx + dx;
                float a = wA[dy * 5 + dx], bw = wB[dy * 5 + dx];
#pragma unroll
                for (int c4 = 0; c4 < 4; ++c4) {
                    f32x4 xv = *(const f32x4*)&xt[pos * 20 + c4 * 4];
                    accA[c4 * 4 + 0] = fmaf(a, xv[0], accA[c4 * 4 + 0]);
                    accA[c4 * 4 + 1] = fmaf(a, xv[1], accA[c4 * 4 + 1]);
                    accA[c4 * 4 + 2] = fmaf(a, xv[2], accA[c4 * 4 + 2]);
                    accA[c4 * 4 + 3] = fmaf(a, xv[3], accA[c4 * 4 + 3]);
                    accB[c4 * 4 + 0] = fmaf(bw, xv[0], accB[c4 * 4 + 0]);
                    accB[c4 * 4 + 1] = fmaf(bw, xv[1], accB[c4 * 4 + 1]);
                    accB[c4 * 4 + 2] = fmaf(bw, xv[2], accB[c4 * 4 + 2]);
                    accB[c4 * 4 + 3] = fmaf(bw, xv[3], accB[c4 * 4 + 3]);
                }
            }
#pragma unroll
        for (int e = 0; e < 16; ++e) {
            float2 st2;
            st2.x = accA[e]; st2.y = accB[e];
            *(float2*)&op[(size_t)(cbase + e) * 16384] = st2;
        }
    }
    __syncthreads();   // all reads of stage 0 done

    // stage-1 data -> LDS
#pragma unroll
    for (int it = 0; it < 4; ++it) {
        int idx = it * 512 + tid;
        if (idx < 1600) {
            int c4 = idx / 400;
            int hp = idx - c4 * 400;
            *(f32x4*)&xt[hp * 20 + c4 * 4] = pg[it];
        }
    }
    __syncthreads();   // xt = stage 1

    // ---- stage 1 compute ----
    {
        float accA[16], accB[16];
#pragma unroll
        for (int e = 0; e < 16; ++e) { accA[e] = 0.f; accB[e] = 0.f; }
#pragma unroll
        for (int dy = 0; dy < 5; ++dy)
#pragma unroll
            for (int dx = 0; dx < 5; ++dx) {
                int pos = (py + dy) * 20 + pxx + dx;
                float a = wA[dy * 5 + dx], bw = wB[dy * 5 + dx];
#pragma unroll
                for (int c4 = 0; c4 < 4; ++c4) {
                    f32x4 xv = *(const f32x4*)&xt[pos * 20 + c4 * 4];
                    accA[c4 * 4 + 0] = fmaf(a, xv[0], accA[c4 * 4 + 0]);
                    accA[c4 * 4 + 1] = fmaf(a, xv[1], accA[c4 * 4 + 1]);
                    accA[c4 * 4 + 2] = fmaf(a, xv[2], accA[c4 * 4 + 2]);
                    accA[c4 * 4 + 3] = fmaf(a, xv[3], accA[c4 * 4 + 3]);
                    accB[c4 * 4 + 0] = fmaf(bw, xv[0], accB[c4 * 4 + 0]);
                    accB[c4 * 4 + 1] = fmaf(bw, xv[1], accB[c4 * 4 + 1]);
                    accB[c4 * 4 + 2] = fmaf(bw, xv[2], accB[c4 * 4 + 2]);
                    accB[c4 * 4 + 3] = fmaf(bw, xv[3], accB[c4 * 4 + 3]);
                }
            }
#pragma unroll
        for (int e = 0; e < 16; ++e) {
            float2 st2;
            st2.x = accA[e]; st2.y = accB[e];
            *(float2*)&op[(size_t)(cbase + 16 + e) * 16384] = st2;
        }
    }
}

extern "C" void kernel_launch(void* const* d_in, const int* in_sizes, int n_in,
                              void* d_out, int out_size, void* d_ws, size_t ws_size,
                              hipStream_t stream) {
    const float* x      = (const float*)d_in[0];
    const float* comp_w = (const float*)d_in[1];
    const float* comp_g = (const float*)d_in[2];
    const float* comp_b = (const float*)d_in[3];
    const float* enc_w  = (const float*)d_in[4];
    const float* enc_g  = (const float*)d_in[5];
    const float* enc_b  = (const float*)d_in[6];
    float* out = (float*)d_out;

    float* ws = (float*)d_ws;
    __bf16* t1c = (__bf16*)ws;             // 8*4096*64 bf16 = 4 MB
    float* t2c  = ws + 1048576;            // 8*25*4096*4 fp32 = 13.1 MB (transposed layout)
    float* st   = ws + 1048576 + 3670016;
    float* csum = st;                      // 64
    float* csq  = st + 64;                 // 64
    float* esum = st + 128;                // 112
    float* esq  = st + 240;                // 112
    __bf16* wprep = (__bf16*)(st + 352);   // 112*576 bf16

    hipMemsetAsync(st, 0, 352 * sizeof(float), stream);
    k_conv1<<<512, 256, 0, stream>>>(x, comp_w, enc_w, t1c, csum, csq, wprep);
    k_conv3<<<1024, 256, 0, stream>>>(t1c, wprep, csum, csq, comp_g, comp_b, t2c, esum, esq);
    k_carafe<<<512, 512, 0, stream>>>(x, t2c, esum, esq, enc_g, enc_b, out);
}